// Round 10
// baseline (322.702 us; speedup 1.0000x reference)
//
#include <hip/hip_runtime.h>
#include <stdint.h>
#include <stddef.h>

typedef __attribute__((ext_vector_type(8))) short short8;
typedef __attribute__((ext_vector_type(4))) float floatx4;

#define CI 128
#define CO 128
#define SP 32768          // 32*32*32
#define BATCH 8
#define STYLED 512
#define KV 3456           // CI*27

typedef __attribute__((address_space(1))) const void gvoid_t;
typedef __attribute__((address_space(3))) void lvoid_t;
__device__ __forceinline__ void gload16(const void* g, void* l) {
    __builtin_amdgcn_global_load_lds((gvoid_t*)g, (lvoid_t*)l, 16, 0, 0);
}

__device__ __forceinline__ short f2bf(float f) {
    uint32_t u = __builtin_bit_cast(uint32_t, f);
    u = (u + 0x7FFFu + ((u >> 16) & 1u)) >> 16;
    return (short)(u & 0xFFFFu);
}

// style_m[b][i] = 1 + affine_b[i] + sum_d s[b][d]*affine_w[i][d]; block 0 zeros zp
__global__ void k_style(const float* __restrict__ s, const float* __restrict__ aw,
                        const float* __restrict__ ab, float* __restrict__ m,
                        float* __restrict__ zp) {
    __shared__ float ssh[STYLED];
    int b = blockIdx.x;
    int i = threadIdx.x;  // 128 threads
    if (b == 0 && i < 64) zp[i] = 0.f;   // 256B zeropage
    for (int r = 0; r < STYLED / 128; ++r) ssh[r * 128 + i] = s[b * STYLED + r * 128 + i];
    __syncthreads();
    float acc = ab[i] + 1.0f;
    const float4* awr = (const float4*)(aw + (size_t)i * STYLED);
    for (int d4 = 0; d4 < STYLED / 4; ++d4) {
        float4 v = awr[d4];
        acc += v.x * ssh[d4 * 4] + v.y * ssh[d4 * 4 + 1] + v.z * ssh[d4 * 4 + 2] + v.w * ssh[d4 * 4 + 3];
    }
    m[b * CI + i] = acc;
}

// wmodT[b][kk][q][o][8] : kk = c32*27+tap, q = ci granule (0..3), o = c_out.
// A-fragment for lane (l15,lhi) at row o: contiguous 16B at ((kk*4+lhi)*128+o)*16.
__global__ void k_wmod(const float* __restrict__ w, const float* __restrict__ m,
                       short* __restrict__ wt) {
    int b = blockIdx.x >> 7;
    int o = blockIdx.x & 127;
    int lane = threadIdx.x;   // 64 threads
    const float* wrow = w + (size_t)o * KV;
    const float* mrow = m + b * CI;
    float sum = 0.f;
    for (int e = lane; e < KV; e += 64) {
        int i = e / 27;
        float v = wrow[e] * mrow[i];
        sum += v * v;
    }
    #pragma unroll
    for (int off = 32; off >= 1; off >>= 1) sum += __shfl_xor(sum, off);
    float scale = 1.0f / sqrtf(sum + 1e-8f);
    for (int e = lane; e < KV; e += 64) {
        int i = e / 27;
        int k = e - i * 27;
        float v = wrow[e] * mrow[i] * scale;
        int kk = (i >> 5) * 27 + k;          // ci32 chunk * 27 + tap
        int il = i & 31, q = il >> 3, r = il & 7;
        wt[((((size_t)(b * 108 + kk)) * 4 + q) * 128 + o) * 8 + r] = f2bf(v);
    }
}

// xT[b][sp][ci] bf16 from x[b][ci][z][y][w] f32. Thread = 2 sp, 32 ch (float2 loads).
__global__ void k_xt(const float* __restrict__ x, short* __restrict__ xt) {
    int bid = blockIdx.x;              // 2048 = 8b * 4c * 64spb
    int b = bid >> 8, c = (bid >> 6) & 3, spb = bid & 63;
    int sp = spb * 512 + threadIdx.x * 2;
    const float* src = x + ((size_t)(b * CI + c * 32)) * SP + sp;
    float2 f[32];
    #pragma unroll
    for (int ch = 0; ch < 32; ++ch) f[ch] = *(const float2*)(src + (size_t)ch * SP);
    short8 v0[4], v1[4];
    #pragma unroll
    for (int q = 0; q < 4; ++q)
        #pragma unroll
        for (int j = 0; j < 8; ++j) {
            v0[q][j] = f2bf(f[q * 8 + j].x);
            v1[q][j] = f2bf(f[q * 8 + j].y);
        }
    short* d0 = xt + (size_t)(b * SP + sp) * CI + c * 32;
    #pragma unroll
    for (int q = 0; q < 4; ++q) *(short8*)(d0 + q * 8) = v0[q];
    #pragma unroll
    for (int q = 0; q < 4; ++q) *(short8*)(d0 + CI + q * 8) = v1[q];
}

// Implicit-GEMM conv, weights DIRECT FROM GLOBAL (L1/L2-resident per XCD):
// no weight LDS, no weight staging barriers. Block = (b, ztile2, ytile4),
// 128co x 256sp, 8 waves 2Mx4N, wave tile 64x64, 16x16x32 MFMA.
// x halo in LDS (R2's measured-zero-conflict layout), restaged per ci32 chunk:
// only 2 barriers per chunk, the 27-tap run is barrier-free.
__launch_bounds__(512, 4)
__global__ void k_conv(const short* __restrict__ xt, const short* __restrict__ wt,
                       const float* __restrict__ bias, float* __restrict__ out,
                       const short* __restrict__ zp) {
    __shared__ short lds_x[816 * 32];     // 52,224 B; 64B rows, XOR-granule layout

    int bid = blockIdx.x;
    int b = bid & 7;                 // sample -> XCD affinity (weights L1/L2-resident)
    int t0 = bid >> 3;               // 0..127
    int zt = t0 & 15, yt = t0 >> 4;
    int z0 = zt * 2, y0 = yt * 4;

    int tid = threadIdx.x;
    int lane = tid & 63;
    int wid = tid >> 6;
    int wm = wid >> 2;               // 0..1 : o-tile base wm*64
    int wn = wid & 3;                // 0..3 : spatial tile base wn*64
    int l15 = lane & 15;
    int lhi = lane >> 4;

    const char* xb = (const char*)(xt + (size_t)b * SP * CI);
    const char* wb = (const char*)(wt + (size_t)b * 108 * 4096);
    int wfbase = (lhi * 128 + wm * 64 + l15) * 16;   // A-frag byte offset within tap image

    // hoisted x-halo source offsets: wave-slice ws = wid + 8j, granule = ws*64+lane
    int xoff[7];
    #pragma unroll
    for (int j = 0; j < 7; ++j) {
        int ws = wid + 8 * j;
        int Gl = ws * 64 + lane;
        int rowid = Gl >> 2, g = Gl & 3;
        int q = g ^ ((rowid >> 1) & 3);          // source pre-swizzle
        int zh = rowid / 204; int rr = rowid - zh * 204;
        int yh = rr / 34;     int wh = rr - yh * 34;
        int zz = z0 + zh - 1, yy = y0 + yh - 1, ww = wh - 1;
        bool ok = (ws < 51) && ((unsigned)zz < 32u) && ((unsigned)yy < 32u) && ((unsigned)ww < 32u);
        xoff[j] = ok ? ((zz * 1024 + yy * 32 + ww) * 256 + q * 16) : -1;
    }

    floatx4 acc[4][4];
    #pragma unroll
    for (int a = 0; a < 4; ++a)
        #pragma unroll
        for (int c = 0; c < 4; ++c) acc[a][c] = (floatx4){0.f, 0.f, 0.f, 0.f};

    #pragma unroll 1
    for (int c = 0; c < 4; ++c) {    // c_in chunks of 32
        __builtin_amdgcn_s_barrier();            // prior chunk's lds_x reads retired
        asm volatile("" ::: "memory");
        #pragma unroll
        for (int j = 0; j < 7; ++j) {
            int ws = wid + 8 * j;
            if (ws < 51) {
                const char* src = (xoff[j] >= 0) ? (xb + xoff[j] + c * 64) : (const char*)zp;
                gload16(src, (void*)((char*)lds_x + ws * 1024));
            }
        }
        asm volatile("s_waitcnt vmcnt(0)" ::: "memory");
        __builtin_amdgcn_s_barrier();
        asm volatile("" ::: "memory");

        const char* wc = wb + (size_t)c * 27 * 8192;

        #pragma unroll 1
        for (int kd = 0; kd < 3; ++kd) {
            #pragma unroll 1
            for (int kh = 0; kh < 3; ++kh) {
                #pragma unroll
                for (int kw = 0; kw < 3; ++kw) {
                    // A-fragments straight from global (L1-hot: same image for all
                    // resident waves of this sample on this CU)
                    const char* wa = wc + (size_t)(kd * 9 + kh * 3 + kw) * 8192 + wfbase;
                    short8 af[4];
                    #pragma unroll
                    for (int mf = 0; mf < 4; ++mf)
                        af[mf] = *(const short8*)(wa + mf * 256);

                    short8 bf[4];
                    #pragma unroll
                    for (int nf = 0; nf < 4; ++nf) {
                        int n = wn * 64 + nf * 16;
                        int zi = n >> 7, yi = (n >> 5) & 3;
                        int h = ((zi + kd) * 6 + (yi + kh)) * 34 + (n & 31) + kw + l15;
                        bf[nf] = *(const short8*)((const char*)lds_x + h * 64 +
                                                  ((lhi ^ ((h >> 1) & 3)) << 4));
                    }
                    __builtin_amdgcn_s_setprio(1);
                    #pragma unroll
                    for (int nf = 0; nf < 4; ++nf)
                        #pragma unroll
                        for (int mf = 0; mf < 4; ++mf)
                            acc[mf][nf] = __builtin_amdgcn_mfma_f32_16x16x32_bf16(
                                af[mf], bf[nf], acc[mf][nf], 0, 0, 0);
                    __builtin_amdgcn_s_setprio(0);
                }
            }
        }
    }

    // epilogue: D layout col=lane&15 (spatial), row=(lane>>4)*4+j (c_out)  [R2-verified]
    float bv[4][4];
    #pragma unroll
    for (int mf = 0; mf < 4; ++mf)
        #pragma unroll
        for (int j = 0; j < 4; ++j)
            bv[mf][j] = bias[wm * 64 + mf * 16 + lhi * 4 + j];

    #pragma unroll
    for (int mf = 0; mf < 4; ++mf) {
        int o = wm * 64 + mf * 16 + lhi * 4;
        #pragma unroll
        for (int nf = 0; nf < 4; ++nf) {
            int n = wn * 64 + nf * 16;
            int zi = n >> 7, yi = (n >> 5) & 3, wcol = (n & 31) + l15;
            size_t obase = ((size_t)(b * CO + o)) * SP + (size_t)(z0 + zi) * 1024 + (y0 + yi) * 32 + wcol;
            #pragma unroll
            for (int j = 0; j < 4; ++j)
                out[obase + (size_t)j * SP] = acc[mf][nf][j] + bv[mf][j];
        }
    }
}

extern "C" void kernel_launch(void* const* d_in, const int* in_sizes, int n_in,
                              void* d_out, int out_size, void* d_ws, size_t ws_size,
                              hipStream_t stream) {
    const float* x  = (const float*)d_in[0];
    const float* s  = (const float*)d_in[1];
    const float* w  = (const float*)d_in[2];
    const float* bb = (const float*)d_in[3];
    const float* aw = (const float*)d_in[4];
    const float* ab = (const float*)d_in[5];
    float* out = (float*)d_out;

    // workspace layout
    float* style_m = (float*)d_ws;                                      // 4 KB
    short* wmodT   = (short*)((char*)d_ws + 4096);                      // 8*108*8192 B = 7,077,888 B
    short* xT      = (short*)((char*)d_ws + 4096 + 7077888);            // 67,108,864 B
    float* zpage   = (float*)((char*)d_ws + 4096 + 7077888 + 67108864); // 256 B zeros

    k_style<<<BATCH, 128, 0, stream>>>(s, aw, ab, style_m, zpage);
    k_wmod<<<BATCH * CO, 64, 0, stream>>>(w, style_m, wmodT);
    k_xt<<<BATCH * 4 * 64, 256, 0, stream>>>(x, xT);
    k_conv<<<BATCH * 128, 512, 0, stream>>>(xT, wmodT, bb, out, (const short*)zpage);
}